// Round 9
// baseline (208.908 us; speedup 1.0000x reference)
//
#include <hip/hip_runtime.h>

#define DM   768
#define QKVN 2304
#define SQ   512
#define NB   16
#define NH   12

typedef unsigned short u16;
typedef _Float16 h16;
typedef _Float16 h16x8 __attribute__((ext_vector_type(8)));
typedef float f32x4 __attribute__((ext_vector_type(4)));

__device__ __forceinline__ u16 f2h(float f) {
  h16 h = (h16)f;
  return __builtin_bit_cast(u16, h);
}
__device__ __forceinline__ float h2f(u16 u) {
  return (float)__builtin_bit_cast(h16, u);
}
__device__ __forceinline__ void gload_lds16(const void* g, void* l) {
  __builtin_amdgcn_global_load_lds((__attribute__((address_space(1))) void*)(g),
                                   (__attribute__((address_space(3))) void*)(l), 16, 0, 0);
}

// ---------------- prep: 8x weight convert  U  rope table  U  pass-1 RMSNorm ----------------
struct WPtrs { const float* s[8]; u16* d[8]; };
__global__ __launch_bounds__(256) void prep_k(WPtrs P, const float* __restrict__ invf,
                                              float* __restrict__ tab,
                                              const float* __restrict__ x, const float* __restrict__ nw,
                                              u16* __restrict__ normed) {
  const int bid = blockIdx.x, tid = threadIdx.x;
  if (bid < 4608) {            // weight convert: 8 x 768x768
    int w = bid / 576;
    int i = ((bid % 576) * 256 + tid) * 4;
    float4 v = *reinterpret_cast<const float4*>(P.s[w] + i);
    ushort4 o;
    o.x = f2h(v.x); o.y = f2h(v.y); o.z = f2h(v.z); o.w = f2h(v.w);
    *reinterpret_cast<ushort4*>(P.d[w] + i) = o;
  } else if (bid < 4672) {     // rope table
    int i = (bid - 4608) * 256 + tid;   // 0..16383
    int pos = i >> 5, j = i & 31;
    float a = (float)pos * invf[j];
    float s, c;
    sincosf(a, &s, &c);
    tab[i * 2] = c; tab[i * 2 + 1] = s;
  } else {                     // RMSNorm pass 1: one wave per token
    int wv = tid >> 6, lane = tid & 63;
    size_t t = (size_t)(bid - 4672) * 4 + wv;
    const float* row = x + t * DM;
    float4 v[3];
    float ss = 0.f;
#pragma unroll
    for (int i = 0; i < 3; i++) {
      v[i] = *reinterpret_cast<const float4*>(row + (lane + 64 * i) * 4);
      ss += v[i].x * v[i].x + v[i].y * v[i].y + v[i].z * v[i].z + v[i].w * v[i].w;
    }
#pragma unroll
    for (int d = 1; d < 64; d <<= 1) ss += __shfl_xor(ss, d);
    float rs = rsqrtf(ss * (1.0f / 768.f) + 1e-6f);
    u16* orow = normed + t * DM;
#pragma unroll
    for (int i = 0; i < 3; i++) {
      int c = (lane + 64 * i) * 4;
      float4 wv4 = *reinterpret_cast<const float4*>(nw + c);
      ushort4 o;
      o.x = f2h(v[i].x * rs * wv4.x);
      o.y = f2h(v[i].y * rs * wv4.y);
      o.z = f2h(v[i].z * rs * wv4.z);
      o.w = f2h(v[i].w * rs * wv4.w);
      *reinterpret_cast<ushort4*>(orow + c) = o;
    }
  }
}

// ---------------- RMSNorm pass 2: fp16 input (h1) ----------------
__global__ __launch_bounds__(256) void rms_k(const u16* __restrict__ x, const float* __restrict__ w,
                                             u16* __restrict__ out) {
  int wv = threadIdx.x >> 6, lane = threadIdx.x & 63;
  size_t t = (size_t)blockIdx.x * 4 + wv;
  const u16* row = x + t * DM;
  float4 v[3];
  float ss = 0.f;
#pragma unroll
  for (int i = 0; i < 3; i++) {
    ushort4 rw = *reinterpret_cast<const ushort4*>(row + (lane + 64 * i) * 4);
    v[i].x = h2f(rw.x); v[i].y = h2f(rw.y); v[i].z = h2f(rw.z); v[i].w = h2f(rw.w);
    ss += v[i].x * v[i].x + v[i].y * v[i].y + v[i].z * v[i].z + v[i].w * v[i].w;
  }
#pragma unroll
  for (int d = 1; d < 64; d <<= 1) ss += __shfl_xor(ss, d);
  float rs = rsqrtf(ss * (1.0f / 768.f) + 1e-6f);
  u16* orow = out + t * DM;
#pragma unroll
  for (int i = 0; i < 3; i++) {
    int c = (lane + 64 * i) * 4;
    float4 wv4 = *reinterpret_cast<const float4*>(w + c);
    ushort4 o;
    o.x = f2h(v[i].x * rs * wv4.x);
    o.y = f2h(v[i].y * rs * wv4.y);
    o.z = f2h(v[i].z * rs * wv4.z);
    o.w = f2h(v[i].w * rs * wv4.w);
    *reinterpret_cast<ushort4*>(orow + c) = o;
  }
}

// ---------------- GEMM: C[M=8192,N] = A[M,768] * W[N,768]^T (both fp16, K-major) ----------------
// Round-9: 256x128 tile, BK=32, 4 waves 2x2 (each wave 128x64 out, acc[8][4]).
// Raises FLOP/LDS-byte 21 -> 29 (LDS-port is the measured GEMM bottleneck: round-8 occupancy null).
// 3-buffer counted-vmcnt(6) pipeline; XCD chunking bnb-minor (L2-resident W panel).
template <int CMODE, bool ROPE, int PERM, bool VT>
__global__ __launch_bounds__(256, 2) void gemm_k(const u16* __restrict__ A, const u16* __restrict__ W, int N,
                                              void* __restrict__ C, const void* __restrict__ resid,
                                              const int* __restrict__ pids, const float* __restrict__ tab,
                                              u16* __restrict__ vt) {
  __shared__ __align__(16) char L[3 * 24576];   // 3 bufs x (A 16KB + B 8KB)
  const int tid = threadIdx.x, w = tid >> 6, lane = tid & 63;
  const int wr = w >> 1, wc = w & 1;
  const int nbn = gridDim.y;                    // N/128
  int nf = blockIdx.y * gridDim.x + blockIdx.x;
  int nwg = gridDim.x * nbn;
  int swv = (nf & 7) * (nwg >> 3) + (nf >> 3);  // XCD-contiguous chunks (nwg%8==0)
  const int bm = swv / nbn;                     // bnb-minor within chunk
  const int bnb = swv % nbn;
  const int l15 = lane & 15, l4 = lane >> 4;
  f32x4 acc[8][4] = {};

  const int r0 = tid >> 2, k40 = tid & 3;       // r0 0..63
  const int k4s = k40 ^ ((r0 >> 1) & 3);
  size_t aA[4], aB[2];
#pragma unroll
  for (int e = 0; e < 4; e++) aA[e] = (size_t)(bm * 256 + e * 64 + r0) * 1536 + k4s * 16;
#pragma unroll
  for (int e = 0; e < 2; e++) aB[e] = (size_t)(bnb * 128 + e * 64 + r0) * 1536 + k4s * 16;
  const char* Ab = (const char*)A;
  const char* Wb = (const char*)W;

#define STAGE(T64, Q) do { \
    _Pragma("unroll") \
    for (int e = 0; e < 4; e++) \
      gload_lds16(Ab + aA[e] + (T64), L + (Q) * 24576 + (e * 256 + tid) * 16); \
    _Pragma("unroll") \
    for (int e = 0; e < 2; e++) \
      gload_lds16(Wb + aB[e] + (T64), L + (Q) * 24576 + 16384 + (e * 256 + tid) * 16); \
  } while (0)

  int obA[8], obB[4];
#pragma unroll
  for (int i = 0; i < 8; i++) {
    int rowA = wr * 128 + i * 16 + l15;
    obA[i] = rowA * 64 + ((l4 ^ ((rowA >> 1) & 3)) * 16);
  }
#pragma unroll
  for (int j = 0; j < 4; j++) {
    int rowB = wc * 64 + j * 16 + l15;
    obB[j] = 16384 + rowB * 64 + ((l4 ^ ((rowB >> 1) & 3)) * 16);
  }

  // prologue: stage tiles 0,1; wait stage0 (12 outstanding -> 6)
  STAGE(0, 0); STAGE(64, 1);
  asm volatile("s_waitcnt vmcnt(6)" ::: "memory");
  __builtin_amdgcn_sched_barrier(0);
  __builtin_amdgcn_s_barrier();
  __builtin_amdgcn_sched_barrier(0);

#pragma unroll
  for (int to = 0; to < 8; ++to) {
#pragma unroll
    for (int ti = 0; ti < 3; ++ti) {
      const int t = to * 3 + ti;
      const int tn = (t + 2 < 24) ? (t + 2) : 23;     // tail: dummy re-stage of tile 23
      STAGE(tn * 64, (t + 2) % 3);                    // dest buffer (t-1)%3 is dead
      const char* bq = L + (t % 3) * 24576;
      h16x8 am[8], bn[4];
#pragma unroll
      for (int j = 0; j < 4; j++) bn[j] = *reinterpret_cast<const h16x8*>(bq + obB[j]);
#pragma unroll
      for (int i = 0; i < 8; i++) am[i] = *reinterpret_cast<const h16x8*>(bq + obA[i]);
      __builtin_amdgcn_s_setprio(1);
#pragma unroll
      for (int i = 0; i < 8; i++)
#pragma unroll
        for (int j = 0; j < 4; j++)
          acc[i][j] = __builtin_amdgcn_mfma_f32_16x16x32_f16(am[i], bn[j], acc[i][j], 0, 0, 0);
      __builtin_amdgcn_s_setprio(0);
      asm volatile("s_waitcnt vmcnt(6)" ::: "memory");
      __builtin_amdgcn_sched_barrier(0);
      __builtin_amdgcn_s_barrier();
      __builtin_amdgcn_sched_barrier(0);
    }
  }
#undef STAGE
  asm volatile("s_waitcnt vmcnt(0)" ::: "memory");   // drain dummy stages before exit

  if (VT && bnb >= 12) {
    // V columns -> transposed vt[((b*NH+h)*64+d)*512 + s]; r -> s consecutive => ushort4 store
#pragma unroll
    for (int i = 0; i < 8; i++) {
      int row0 = bm * 256 + wr * 128 + i * 16 + l4 * 4;
      int b = row0 >> 9, s0 = row0 & 511;
#pragma unroll
      for (int j = 0; j < 4; j++) {
        int vcol = bnb * 128 + wc * 64 + j * 16 + l15 - 1536;
        int hh = vcol >> 6, dd = vcol & 63;
        u16* dst = vt + (((size_t)(b * NH + hh) * 64 + dd) << 9) + s0;
        ushort4 o;
        o.x = f2h(acc[i][j][0]); o.y = f2h(acc[i][j][1]);
        o.z = f2h(acc[i][j][2]); o.w = f2h(acc[i][j][3]);
        *reinterpret_cast<ushort4*>(dst) = o;
      }
    }
    return;
  }

  if (ROPE && bnb < 12) {
#pragma unroll
    for (int i = 0; i < 8; i++) {
      int row0 = bm * 256 + wr * 128 + i * 16 + l4 * 4;
#pragma unroll
      for (int r = 0; r < 4; r++) {
        int pos = pids[row0 + r];
        const float* tb = tab + pos * 64;
#pragma unroll
        for (int j = 0; j < 2; j++) {
          float2 cs = *reinterpret_cast<const float2*>(tb + 2 * (j * 16 + l15));
          float x1 = acc[i][j][r], x2 = acc[i][j + 2][r];
          acc[i][j][r]     = x1 * cs.x - x2 * cs.y;
          acc[i][j + 2][r] = x2 * cs.x + x1 * cs.y;
        }
      }
    }
  }
#pragma unroll
  for (int i = 0; i < 8; i++) {
    int row0 = bm * 256 + wr * 128 + i * 16 + l4 * 4;
#pragma unroll
    for (int j = 0; j < 4; j++) {
      int col = bnb * 128 + wc * 64 + j * 16 + l15;
#pragma unroll
      for (int r = 0; r < 4; r++) {
        int rr = row0 + r;
        int orow = (PERM == 0) ? rr : (PERM == 1) ? ((rr & 511) * 16 + (rr >> 9))
                                                  : ((rr & 15) * 512 + (rr >> 4));
        size_t idx = (size_t)orow * N + col;
        float v = acc[i][j][r];
        if (CMODE == 0)      ((u16*)C)[idx] = f2h(v);
        else if (CMODE == 1) ((u16*)C)[idx] = f2h(v + ((const float*)resid)[idx]);
        else                 ((float*)C)[idx] = v + h2f(((const u16*)resid)[idx]);
      }
    }
  }
}

// ---------------- Pass-1 attention: KVBLK=128, dbuf prefetch, gload_lds K + V^T ----------------
__global__ __launch_bounds__(256) void attn1_k(const u16* __restrict__ qkv, const u16* __restrict__ vt,
                                               u16* __restrict__ O) {
  __shared__ __align__(16) char L[2][32768];   // [buf][ K 16KB | Vt 16KB ]
  __shared__ __align__(16) char Pl[4][4096];   // per-wave P [16 q][128 keys] swizzled
  const int qt = blockIdx.x;   // 0..7
  const int bh = blockIdx.y;   // 0..191
  const int b = bh / NH, h = bh % NH;
  const int tid = threadIdx.x, w = tid >> 6, lane = tid & 63;
  const int l15 = lane & 15, l4 = lane >> 4;
  const size_t qoff = ((size_t)(b * SQ + qt * 64 + w * 16 + l15)) * QKVN + h * 64;
  h16x8 qf[2];
  qf[0] = *reinterpret_cast<const h16x8*>(qkv + qoff + 8 * l4);
  qf[1] = *reinterpret_cast<const h16x8*>(qkv + qoff + 32 + 8 * l4);
  f32x4 acco[4] = {};
  float mrun[4] = {-3e38f, -3e38f, -3e38f, -3e38f};
  float lrun[4] = {0.f, 0.f, 0.f, 0.f};
  const int qrow = qt * 64 + w * 16 + l4 * 4;  // + r
  const int nkt = (qt >> 1) + 1;

  const u16* Kg = qkv + (size_t)b * SQ * QKVN + DM + h * 64;   // + key*QKVN
  const int rK0 = tid >> 3;
  const size_t aK0 = (size_t)rK0 * QKVN + (size_t)(((tid & 7) ^ (rK0 & 7)) * 8);
  const u16* Vg = vt + (size_t)bh * 64 * SQ;                   // + d*SQ
  const int dV0 = tid >> 4;
  const size_t aV0 = (size_t)dV0 * SQ + (size_t)(((tid & 15) ^ (dV0 & 15)) * 8);
  const int dst0 = tid * 16;

#define STAGE1(KT, BUF) do { \
    _Pragma("unroll") \
    for (int e = 0; e < 4; e++) \
      gload_lds16(Kg + aK0 + (size_t)e * (32 * QKVN) + (size_t)(KT) * (128 * QKVN), \
                  L[BUF] + dst0 + e * 4096); \
    _Pragma("unroll") \
    for (int e = 0; e < 4; e++) \
      gload_lds16(Vg + aV0 + e * (16 * SQ) + (KT) * 128, \
                  L[BUF] + 16384 + dst0 + e * 4096); \
  } while (0)

  STAGE1(0, 0);
  asm volatile("s_waitcnt vmcnt(0)" ::: "memory");
  __builtin_amdgcn_sched_barrier(0);
  __builtin_amdgcn_s_barrier();
  __builtin_amdgcn_sched_barrier(0);

  for (int kt = 0; kt < nkt; ++kt) {
    const int cur = kt & 1;
    if (kt + 1 < nkt) STAGE1(kt + 1, cur ^ 1);
    const char* Kb = L[cur];
    const char* Vb = L[cur] + 16384;
    f32x4 sc[8] = {};
    __builtin_amdgcn_s_setprio(1);
#pragma unroll
    for (int kk = 0; kk < 2; kk++) {
#pragma unroll
      for (int j = 0; j < 8; j++) {
        int row = j * 16 + l15;
        int off = row * 128 + (((kk * 4 + l4) ^ (row & 7)) * 16);
        h16x8 kf = *reinterpret_cast<const h16x8*>(Kb + off);
        sc[j] = __builtin_amdgcn_mfma_f32_16x16x32_f16(qf[kk], kf, sc[j], 0, 0, 0);
      }
    }
    __builtin_amdgcn_s_setprio(0);
    float pv[8][4];
#pragma unroll
    for (int j = 0; j < 8; j++)
#pragma unroll
      for (int r = 0; r < 4; r++) pv[j][r] = sc[j][r];
    if (kt == nkt - 1) {  // tile containing the causal diagonal
#pragma unroll
      for (int r = 0; r < 4; r++) {
        int q = qrow + r;
#pragma unroll
        for (int j = 0; j < 8; j++) {
          int key = kt * 128 + j * 16 + l15;
          if (key > q) pv[j][r] = -1e30f;
        }
      }
    }
    float al[4];
#pragma unroll
    for (int r = 0; r < 4; r++) {
      float t0 = fmaxf(fmaxf(pv[0][r], pv[1][r]), fmaxf(pv[2][r], pv[3][r]));
      float t1 = fmaxf(fmaxf(pv[4][r], pv[5][r]), fmaxf(pv[6][r], pv[7][r]));
      float tm = fmaxf(t0, t1);
      tm = fmaxf(tm, __shfl_xor(tm, 1)); tm = fmaxf(tm, __shfl_xor(tm, 2));
      tm = fmaxf(tm, __shfl_xor(tm, 4)); tm = fmaxf(tm, __shfl_xor(tm, 8));
      float mn = fmaxf(mrun[r], tm);
      al[r] = __expf(mrun[r] - mn);
      mrun[r] = mn;
      float ts = 0.f;
#pragma unroll
      for (int j = 0; j < 8; j++) { float p = __expf(pv[j][r] - mn); pv[j][r] = p; ts += p; }
      ts += __shfl_xor(ts, 1); ts += __shfl_xor(ts, 2); ts += __shfl_xor(ts, 4); ts += __shfl_xor(ts, 8);
      lrun[r] = lrun[r] * al[r] + ts;
    }
#pragma unroll
    for (int j = 0; j < 4; j++)
#pragma unroll
      for (int r = 0; r < 4; r++) acco[j][r] *= al[r];
    char* pw = Pl[w];
#pragma unroll
    for (int r = 0; r < 4; r++) {
      int q = l4 * 4 + r;
#pragma unroll
      for (int j = 0; j < 8; j++) {
        int cw = j * 2 + (l15 >> 3);
        int byte = q * 256 + ((cw ^ (q & 15)) * 16) + (l15 & 7) * 2;
        *(u16*)(pw + byte) = f2h(pv[j][r]);
      }
    }
    asm volatile("s_waitcnt lgkmcnt(0)" ::: "memory");
    __builtin_amdgcn_sched_barrier(0);
    __builtin_amdgcn_s_setprio(1);
#pragma unroll
    for (int kk = 0; kk < 4; kk++) {
      h16x8 pa = *reinterpret_cast<const h16x8*>(pw + l15 * 256 + (((kk * 4 + l4) ^ l15) * 16));
#pragma unroll
      for (int j = 0; j < 4; j++) {
        int d = j * 16 + l15;
        int voff = d * 256 + (((kk * 4 + l4) ^ (d & 15)) * 16);
        h16x8 vf = *reinterpret_cast<const h16x8*>(Vb + voff);
        acco[j] = __builtin_amdgcn_mfma_f32_16x16x32_f16(pa, vf, acco[j], 0, 0, 0);
      }
    }
    __builtin_amdgcn_s_setprio(0);
    asm volatile("s_waitcnt vmcnt(0)" ::: "memory");
    __builtin_amdgcn_sched_barrier(0);
    __builtin_amdgcn_s_barrier();
    __builtin_amdgcn_sched_barrier(0);
  }
#undef STAGE1
#pragma unroll
  for (int r = 0; r < 4; r++) {
    float inv = 1.f / lrun[r];
    size_t orow = ((size_t)(b * SQ + qrow + r)) * DM + h * 64;
#pragma unroll
    for (int j = 0; j < 4; j++) O[orow + j * 16 + l15] = f2h(acco[j][r] * inv);
  }
}

// ---------------- Pass-2 attention: 16x16 per (s,h), one wave each (s-major qkv) ----------------
__global__ __launch_bounds__(256) void attn2_k(const u16* __restrict__ qkv, const float* __restrict__ gmask,
                                               u16* __restrict__ O) {
  __shared__ float Pl[4][16][16];
  __shared__ float Vl[4][16][68];
  const int tid = threadIdx.x, w = tid >> 6, lane = tid & 63;
  const int idx = blockIdx.x * 4 + w;
  const int s = idx / NH, h = idx % NH;
  const int l15 = lane & 15, l4 = lane >> 4;
  const size_t base = ((size_t)(s * 16 + l15)) * QKVN + h * 64;
  h16x8 qf0 = *reinterpret_cast<const h16x8*>(qkv + base + 8 * l4);
  h16x8 qf1 = *reinterpret_cast<const h16x8*>(qkv + base + 32 + 8 * l4);
  h16x8 kf0 = *reinterpret_cast<const h16x8*>(qkv + base + DM + 8 * l4);
  h16x8 kf1 = *reinterpret_cast<const h16x8*>(qkv + base + DM + 32 + 8 * l4);
  f32x4 sc = {};
  sc = __builtin_amdgcn_mfma_f32_16x16x32_f16(qf0, kf0, sc, 0, 0, 0);
  sc = __builtin_amdgcn_mfma_f32_16x16x32_f16(qf1, kf1, sc, 0, 0, 0);
  {
    int key = lane >> 2, d0 = (lane & 3) * 16;
    const u16* vsrc = qkv + ((size_t)(s * 16 + key)) * QKVN + 2 * DM + h * 64 + d0;
#pragma unroll
    for (int i = 0; i < 16; i += 4) {
      ushort4 vv = *reinterpret_cast<const ushort4*>(vsrc + i);
      Vl[w][key][d0 + i + 0] = h2f(vv.x);
      Vl[w][key][d0 + i + 1] = h2f(vv.y);
      Vl[w][key][d0 + i + 2] = h2f(vv.z);
      Vl[w][key][d0 + i + 3] = h2f(vv.w);
    }
  }
  const float* gm = gmask + ((size_t)s * NH + h) * 256;
#pragma unroll
  for (int r = 0; r < 4; r++) {
    float v = sc[r] + gm[(l4 * 4 + r) * 16 + l15];
    float mx = v;
    mx = fmaxf(mx, __shfl_xor(mx, 1)); mx = fmaxf(mx, __shfl_xor(mx, 2));
    mx = fmaxf(mx, __shfl_xor(mx, 4)); mx = fmaxf(mx, __shfl_xor(mx, 8));
    float p = __expf(v - mx);
    float su = p;
    su += __shfl_xor(su, 1); su += __shfl_xor(su, 2); su += __shfl_xor(su, 4); su += __shfl_xor(su, 8);
    Pl[w][l4 * 4 + r][l15] = p / su;
  }
  asm volatile("s_waitcnt lgkmcnt(0)" ::: "memory");
  __builtin_amdgcn_sched_barrier(0);
  const int q = lane >> 2, d0 = (lane & 3) * 16;
  float o[16] = {};
#pragma unroll
  for (int key = 0; key < 16; key++) {
    float pp = Pl[w][q][key];
#pragma unroll
    for (int dd = 0; dd < 16; dd += 4) {
      float4 vv = *reinterpret_cast<const float4*>(&Vl[w][key][d0 + dd]);
      o[dd + 0] += pp * vv.x; o[dd + 1] += pp * vv.y; o[dd + 2] += pp * vv.z; o[dd + 3] += pp * vv.w;
    }
  }
  u16* orow = O + ((size_t)(s * 16 + q)) * DM + h * 64 + d0;
#pragma unroll
  for (int i = 0; i < 16; i += 4) {
    ushort4 ov;
    ov.x = f2h(o[i]); ov.y = f2h(o[i + 1]); ov.z = f2h(o[i + 2]); ov.w = f2h(o[i + 3]);
    *reinterpret_cast<ushort4*>(orow + i) = ov;
  }
}

// ---------------- launch ----------------
extern "C" void kernel_launch(void* const* d_in, const int* in_sizes, int n_in,
                              void* d_out, int out_size, void* d_ws, size_t ws_size,
                              hipStream_t stream) {
  const float* hidden = (const float*)d_in[0];
  const int*   pids   = (const int*)d_in[1];
  const float* gmask  = (const float*)d_in[3];
  const float* tq = (const float*)d_in[4];
  const float* tk = (const float*)d_in[5];
  const float* tv = (const float*)d_in[6];
  const float* to_ = (const float*)d_in[7];
  const float* tnw = (const float*)d_in[8];
  const float* gq = (const float*)d_in[9];
  const float* gk = (const float*)d_in[10];
  const float* gv = (const float*)d_in[11];
  const float* go = (const float*)d_in[12];
  const float* gnw = (const float*)d_in[13];
  const float* invf = (const float*)d_in[14];
  float* out = (float*)d_out;
  char* ws = (char*)d_ws;

  u16*   wq1    = (u16*)(ws);                   // 2304x768 fp16
  u16*   wo1    = (u16*)(ws + 3538944);         // 768x768
  u16*   wq2    = (u16*)(ws + 4718592);
  u16*   wo2    = (u16*)(ws + 8257536);
  float* tab    = (float*)(ws + 9437184);       // 512x32x2 f32
  u16*   normed = (u16*)(ws + 9568256);         // 8192x768 fp16
  u16*   obuf   = (u16*)(ws + 22151168);        // 8192x768 fp16
  u16*   h1     = (u16*)(ws + 34734080);        // 8192x768 fp16 residual spine
  u16*   qkv    = (u16*)(ws + 59899904);        // 8192x2304 fp16
  u16*   vt     = (u16*)(ws + 97648640);        // 192 x 64 x 512 fp16 (12.6 MB)

  const int WN = 768 * 768;
  WPtrs P;
  P.s[0] = tq;  P.d[0] = wq1;
  P.s[1] = tk;  P.d[1] = wq1 + WN;
  P.s[2] = tv;  P.d[2] = wq1 + 2 * WN;
  P.s[3] = to_; P.d[3] = wo1;
  P.s[4] = gq;  P.d[4] = wq2;
  P.s[5] = gk;  P.d[5] = wq2 + WN;
  P.s[6] = gv;  P.d[6] = wq2 + 2 * WN;
  P.s[7] = go;  P.d[7] = wo2;

  // pass 1 (time attention, causal + fused RoPE; V written transposed by GEMM epilogue)
  prep_k<<<6720, 256, 0, stream>>>(P, invf, tab, hidden, tnw, normed);
  gemm_k<0, true, 0, true><<<dim3(32, 18), 256, 0, stream>>>(normed, wq1, QKVN, qkv, nullptr, pids, tab, vt);
  attn1_k<<<dim3(8, 192), 256, 0, stream>>>(qkv, vt, obuf);
  gemm_k<1, false, 0, false><<<dim3(32, 6), 256, 0, stream>>>(obuf, wo1, DM, h1, hidden, nullptr, nullptr, nullptr);

  // pass 2 (group attention over batch dim; s-major token order)
  rms_k<<<2048, 256, 0, stream>>>(h1, gnw, normed);
  gemm_k<0, false, 1, false><<<dim3(32, 18), 256, 0, stream>>>(normed, wq2, QKVN, qkv, nullptr, nullptr, nullptr, nullptr);
  attn2_k<<<1536, 256, 0, stream>>>(qkv, gmask, obuf);
  gemm_k<2, false, 2, false><<<dim3(32, 6), 256, 0, stream>>>(obuf, wo2, DM, out, h1, nullptr, nullptr, nullptr);
}

// Round 10
// 196.964 us; speedup vs baseline: 1.0606x; 1.0606x over previous
//
#include <hip/hip_runtime.h>

#define DM   768
#define QKVN 2304
#define SQ   512
#define NB   16
#define NH   12

typedef unsigned short u16;
typedef _Float16 h16;
typedef _Float16 h16x8 __attribute__((ext_vector_type(8)));
typedef float f32x4 __attribute__((ext_vector_type(4)));

__device__ __forceinline__ u16 f2h(float f) {
  h16 h = (h16)f;
  return __builtin_bit_cast(u16, h);
}
__device__ __forceinline__ float h2f(u16 u) {
  return (float)__builtin_bit_cast(h16, u);
}
__device__ __forceinline__ void gload_lds16(const void* g, void* l) {
  __builtin_amdgcn_global_load_lds((__attribute__((address_space(1))) void*)(g),
                                   (__attribute__((address_space(3))) void*)(l), 16, 0, 0);
}

// ---------------- prep: 8x weight convert (norm-w folded)  U  rope table  U  xh + rs1 ----------------
struct WPtrs { const float* s[8]; u16* d[8]; };
__global__ __launch_bounds__(256) void prep_k(WPtrs P, const float* __restrict__ invf,
                                              float* __restrict__ tab,
                                              const float* __restrict__ x,
                                              const float* __restrict__ tnw, const float* __restrict__ gnw,
                                              u16* __restrict__ xh, float* __restrict__ rs1) {
  const int bid = blockIdx.x, tid = threadIdx.x;
  if (bid < 4608) {            // weight convert: 8 x 768x768 ; fold tnw into QKV1, gnw into QKV2
    int w = bid / 576;
    int i = ((bid % 576) * 256 + tid) * 4;
    float4 v = *reinterpret_cast<const float4*>(P.s[w] + i);
    if (w < 3 || (w >= 4 && w < 7)) {
      const float* nw = (w < 3) ? tnw : gnw;
      int k = i % 768;
      float4 f = *reinterpret_cast<const float4*>(nw + k);
      v.x *= f.x; v.y *= f.y; v.z *= f.z; v.w *= f.w;
    }
    ushort4 o;
    o.x = f2h(v.x); o.y = f2h(v.y); o.z = f2h(v.z); o.w = f2h(v.w);
    *reinterpret_cast<ushort4*>(P.d[w] + i) = o;
  } else if (bid < 4672) {     // rope table
    int i = (bid - 4608) * 256 + tid;   // 0..16383
    int pos = i >> 5, j = i & 31;
    float a = (float)pos * invf[j];
    float s, c;
    sincosf(a, &s, &c);
    tab[i * 2] = c; tab[i * 2 + 1] = s;
  } else {                     // pass-1: xh = fp16(x), rs1 = rsqrt(mean(x^2)+eps)
    int wv = tid >> 6, lane = tid & 63;
    size_t t = (size_t)(bid - 4672) * 4 + wv;
    const float* row = x + t * DM;
    float4 v[3];
    float ss = 0.f;
#pragma unroll
    for (int i = 0; i < 3; i++) {
      v[i] = *reinterpret_cast<const float4*>(row + (lane + 64 * i) * 4);
      ss += v[i].x * v[i].x + v[i].y * v[i].y + v[i].z * v[i].z + v[i].w * v[i].w;
    }
#pragma unroll
    for (int d = 1; d < 64; d <<= 1) ss += __shfl_xor(ss, d);
    u16* orow = xh + t * DM;
#pragma unroll
    for (int i = 0; i < 3; i++) {
      int c = (lane + 64 * i) * 4;
      ushort4 o;
      o.x = f2h(v[i].x); o.y = f2h(v[i].y); o.z = f2h(v[i].z); o.w = f2h(v[i].w);
      *reinterpret_cast<ushort4*>(orow + c) = o;
    }
    if (lane == 0) rs1[t] = rsqrtf(ss * (1.0f / 768.f) + 1e-6f);
  }
}

// ---------------- rs2: per-row rsqrt(mean(h1^2)+eps), h1 fp16 ----------------
__global__ __launch_bounds__(256) void rs2_k(const u16* __restrict__ x, float* __restrict__ rs2) {
  int wv = threadIdx.x >> 6, lane = threadIdx.x & 63;
  size_t t = (size_t)blockIdx.x * 4 + wv;
  const u16* row = x + t * DM;
  float ss = 0.f;
#pragma unroll
  for (int i = 0; i < 3; i++) {
    ushort4 rw = *reinterpret_cast<const ushort4*>(row + (lane + 64 * i) * 4);
    float a = h2f(rw.x), b = h2f(rw.y), c = h2f(rw.z), d = h2f(rw.w);
    ss += a * a + b * b + c * c + d * d;
  }
#pragma unroll
  for (int d = 1; d < 64; d <<= 1) ss += __shfl_xor(ss, d);
  if (lane == 0) rs2[t] = rsqrtf(ss * (1.0f / 768.f) + 1e-6f);
}

// ---------------- GEMM: C[M=8192,N] = A[M,768] * W[N,768]^T (both fp16, K-major) ----------------
// Round-8 config (best measured): 128x128 tile, BK=32, 3-buffer counted-vmcnt(4), setprio,
// XCD chunking bnb-minor. RS: epilogue row-scale (RMSNorm folded: W' carries norm-w, rsb carries rs).
// CMODE: 0 = fp16 C; 1 = fp16 C = acc + fp16 resid; 2 = f32 C = acc + fp16 resid.
template <int CMODE, bool ROPE, int PERM, bool VT, bool RS>
__global__ __launch_bounds__(256, 3) void gemm_k(const u16* __restrict__ A, const u16* __restrict__ W, int N,
                                              void* __restrict__ C, const void* __restrict__ resid,
                                              const int* __restrict__ pids, const float* __restrict__ tab,
                                              u16* __restrict__ vt, const float* __restrict__ rsb) {
  __shared__ __align__(16) char L[3 * 16384];   // 3 bufs x (A 8KB + B 8KB)
  const int tid = threadIdx.x, w = tid >> 6, lane = tid & 63;
  const int wr = w >> 1, wc = w & 1;
  const int nbn = gridDim.y;                    // N/128
  int nf = blockIdx.y * gridDim.x + blockIdx.x;
  int nwg = gridDim.x * nbn;
  int swv = (nf & 7) * (nwg >> 3) + (nf >> 3);  // XCD-contiguous chunks (nwg%8==0)
  const int bm = swv / nbn;                     // bnb-minor within chunk
  const int bnb = swv % nbn;
  const int l15 = lane & 15, l4 = lane >> 4;
  f32x4 acc[4][4] = {};

  const int r0 = tid >> 2, k40 = tid & 3;
  const int k4s = k40 ^ ((r0 >> 1) & 3);
  const size_t aA0 = (size_t)(bm * 128 + r0) * 1536 + k4s * 16;
  const size_t aA1 = (size_t)(bm * 128 + r0 + 64) * 1536 + k4s * 16;
  const size_t aB0 = (size_t)(bnb * 128 + r0) * 1536 + k4s * 16;
  const size_t aB1 = (size_t)(bnb * 128 + r0 + 64) * 1536 + k4s * 16;
  const int dc0 = tid * 16, dc1 = dc0 + 4096;
  const char* Ab = (const char*)A;
  const char* Wb = (const char*)W;

#define STAGE(T64, Q) do { \
    gload_lds16(Ab + aA0 + (T64), L + (Q) * 16384 + dc0); \
    gload_lds16(Ab + aA1 + (T64), L + (Q) * 16384 + dc1); \
    gload_lds16(Wb + aB0 + (T64), L + (Q) * 16384 + 8192 + dc0); \
    gload_lds16(Wb + aB1 + (T64), L + (Q) * 16384 + 8192 + dc1); \
  } while (0)

  int obA[4], obB[4];
#pragma unroll
  for (int i = 0; i < 4; i++) {
    int rowA = wr * 64 + i * 16 + l15;
    obA[i] = rowA * 64 + ((l4 ^ ((rowA >> 1) & 3)) * 16);
    int rowB = wc * 64 + i * 16 + l15;
    obB[i] = 8192 + rowB * 64 + ((l4 ^ ((rowB >> 1) & 3)) * 16);
  }

  STAGE(0, 0); STAGE(64, 1);
  asm volatile("s_waitcnt vmcnt(4)" ::: "memory");
  __builtin_amdgcn_sched_barrier(0);
  __builtin_amdgcn_s_barrier();
  __builtin_amdgcn_sched_barrier(0);

#pragma unroll
  for (int to = 0; to < 8; ++to) {
#pragma unroll
    for (int ti = 0; ti < 3; ++ti) {
      const int t = to * 3 + ti;
      const int tn = (t + 2 < 24) ? (t + 2) : 23;     // tail: dummy re-stage of tile 23
      STAGE(tn * 64, (t + 2) % 3);                    // dest buffer (t-1)%3 is dead
      const char* bq = L + (t % 3) * 16384;
      h16x8 am[4], bn[4];
#pragma unroll
      for (int i = 0; i < 4; i++) am[i] = *reinterpret_cast<const h16x8*>(bq + obA[i]);
#pragma unroll
      for (int j = 0; j < 4; j++) bn[j] = *reinterpret_cast<const h16x8*>(bq + obB[j]);
      __builtin_amdgcn_s_setprio(1);
#pragma unroll
      for (int i = 0; i < 4; i++)
#pragma unroll
        for (int j = 0; j < 4; j++)
          acc[i][j] = __builtin_amdgcn_mfma_f32_16x16x32_f16(am[i], bn[j], acc[i][j], 0, 0, 0);
      __builtin_amdgcn_s_setprio(0);
      asm volatile("s_waitcnt vmcnt(4)" ::: "memory");
      __builtin_amdgcn_sched_barrier(0);
      __builtin_amdgcn_s_barrier();
      __builtin_amdgcn_sched_barrier(0);
    }
  }
#undef STAGE
  asm volatile("s_waitcnt vmcnt(0)" ::: "memory");   // drain dummy stages before exit

  if (RS) {  // RMSNorm row scale (norm-w already folded into W')
#pragma unroll
    for (int i = 0; i < 4; i++) {
      int row0 = bm * 128 + wr * 64 + i * 16 + l4 * 4;
#pragma unroll
      for (int r = 0; r < 4; r++) {
        float s = rsb[row0 + r];
#pragma unroll
        for (int j = 0; j < 4; j++) acc[i][j][r] *= s;
      }
    }
  }

  if (VT && bnb >= 12) {
    // V columns -> transposed vt[((b*NH+h)*64+d)*512 + s]; r -> s consecutive => ushort4 store
#pragma unroll
    for (int i = 0; i < 4; i++) {
      int row0 = bm * 128 + wr * 64 + i * 16 + l4 * 4;
      int b = row0 >> 9, s0 = row0 & 511;
#pragma unroll
      for (int j = 0; j < 4; j++) {
        int vcol = bnb * 128 + wc * 64 + j * 16 + l15 - 1536;
        int hh = vcol >> 6, dd = vcol & 63;
        u16* dst = vt + (((size_t)(b * NH + hh) * 64 + dd) << 9) + s0;
        ushort4 o;
        o.x = f2h(acc[i][j][0]); o.y = f2h(acc[i][j][1]);
        o.z = f2h(acc[i][j][2]); o.w = f2h(acc[i][j][3]);
        *reinterpret_cast<ushort4*>(dst) = o;
      }
    }
    return;
  }

  if (ROPE && bnb < 12) {
#pragma unroll
    for (int i = 0; i < 4; i++) {
      int row0 = bm * 128 + wr * 64 + i * 16 + l4 * 4;
#pragma unroll
      for (int r = 0; r < 4; r++) {
        int pos = pids[row0 + r];
        const float* tb = tab + pos * 64;
#pragma unroll
        for (int j = 0; j < 2; j++) {
          float2 cs = *reinterpret_cast<const float2*>(tb + 2 * (j * 16 + l15));
          float x1 = acc[i][j][r], x2 = acc[i][j + 2][r];
          acc[i][j][r]     = x1 * cs.x - x2 * cs.y;
          acc[i][j + 2][r] = x2 * cs.x + x1 * cs.y;
        }
      }
    }
  }
#pragma unroll
  for (int i = 0; i < 4; i++) {
    int row0 = bm * 128 + wr * 64 + i * 16 + l4 * 4;
#pragma unroll
    for (int j = 0; j < 4; j++) {
      int col = bnb * 128 + wc * 64 + j * 16 + l15;
#pragma unroll
      for (int r = 0; r < 4; r++) {
        int rr = row0 + r;
        int orow = (PERM == 0) ? rr : (PERM == 1) ? ((rr & 511) * 16 + (rr >> 9))
                                                  : ((rr & 15) * 512 + (rr >> 4));
        size_t idx = (size_t)orow * N + col;
        float v = acc[i][j][r];
        if (CMODE == 0)      ((u16*)C)[idx] = f2h(v);
        else if (CMODE == 1) ((u16*)C)[idx] = f2h(v + h2f(((const u16*)resid)[idx]));
        else                 ((float*)C)[idx] = v + h2f(((const u16*)resid)[idx]);
      }
    }
  }
}

// ---------------- Pass-1 attention: KVBLK=128, dbuf prefetch, gload_lds K + V^T, XCD-chunked ----------------
__global__ __launch_bounds__(256) void attn1_k(const u16* __restrict__ qkv, const u16* __restrict__ vt,
                                               u16* __restrict__ O) {
  __shared__ __align__(16) char L[2][32768];   // [buf][ K 16KB | Vt 16KB ]
  __shared__ __align__(16) char Pl[4][4096];   // per-wave P [16 q][128 keys] swizzled
  // XCD swizzle: keep all 8 qt of one bh on one XCD (K/V reuse in that XCD's L2)
  int nf = blockIdx.y * 8 + blockIdx.x;        // = bh*8 + qt ; nwg = 1536, %8==0
  int swv = (nf & 7) * 192 + (nf >> 3);
  const int qt = swv & 7;
  const int bh = swv >> 3;
  const int b = bh / NH, h = bh % NH;
  const int tid = threadIdx.x, w = tid >> 6, lane = tid & 63;
  const int l15 = lane & 15, l4 = lane >> 4;
  const size_t qoff = ((size_t)(b * SQ + qt * 64 + w * 16 + l15)) * QKVN + h * 64;
  h16x8 qf[2];
  qf[0] = *reinterpret_cast<const h16x8*>(qkv + qoff + 8 * l4);
  qf[1] = *reinterpret_cast<const h16x8*>(qkv + qoff + 32 + 8 * l4);
  f32x4 acco[4] = {};
  float mrun[4] = {-3e38f, -3e38f, -3e38f, -3e38f};
  float lrun[4] = {0.f, 0.f, 0.f, 0.f};
  const int qrow = qt * 64 + w * 16 + l4 * 4;  // + r
  const int nkt = (qt >> 1) + 1;

  const u16* Kg = qkv + (size_t)b * SQ * QKVN + DM + h * 64;   // + key*QKVN
  const int rK0 = tid >> 3;
  const size_t aK0 = (size_t)rK0 * QKVN + (size_t)(((tid & 7) ^ (rK0 & 7)) * 8);
  const u16* Vg = vt + (size_t)bh * 64 * SQ;                   // + d*SQ
  const int dV0 = tid >> 4;
  const size_t aV0 = (size_t)dV0 * SQ + (size_t)(((tid & 15) ^ (dV0 & 15)) * 8);
  const int dst0 = tid * 16;

#define STAGE1(KT, BUF) do { \
    _Pragma("unroll") \
    for (int e = 0; e < 4; e++) \
      gload_lds16(Kg + aK0 + (size_t)e * (32 * QKVN) + (size_t)(KT) * (128 * QKVN), \
                  L[BUF] + dst0 + e * 4096); \
    _Pragma("unroll") \
    for (int e = 0; e < 4; e++) \
      gload_lds16(Vg + aV0 + e * (16 * SQ) + (KT) * 128, \
                  L[BUF] + 16384 + dst0 + e * 4096); \
  } while (0)

  STAGE1(0, 0);
  asm volatile("s_waitcnt vmcnt(0)" ::: "memory");
  __builtin_amdgcn_sched_barrier(0);
  __builtin_amdgcn_s_barrier();
  __builtin_amdgcn_sched_barrier(0);

  for (int kt = 0; kt < nkt; ++kt) {
    const int cur = kt & 1;
    if (kt + 1 < nkt) STAGE1(kt + 1, cur ^ 1);
    const char* Kb = L[cur];
    const char* Vb = L[cur] + 16384;
    f32x4 sc[8] = {};
    __builtin_amdgcn_s_setprio(1);
#pragma unroll
    for (int kk = 0; kk < 2; kk++) {
#pragma unroll
      for (int j = 0; j < 8; j++) {
        int row = j * 16 + l15;
        int off = row * 128 + (((kk * 4 + l4) ^ (row & 7)) * 16);
        h16x8 kf = *reinterpret_cast<const h16x8*>(Kb + off);
        sc[j] = __builtin_amdgcn_mfma_f32_16x16x32_f16(qf[kk], kf, sc[j], 0, 0, 0);
      }
    }
    __builtin_amdgcn_s_setprio(0);
    float pv[8][4];
#pragma unroll
    for (int j = 0; j < 8; j++)
#pragma unroll
      for (int r = 0; r < 4; r++) pv[j][r] = sc[j][r];
    if (kt == nkt - 1) {  // tile containing the causal diagonal
#pragma unroll
      for (int r = 0; r < 4; r++) {
        int q = qrow + r;
#pragma unroll
        for (int j = 0; j < 8; j++) {
          int key = kt * 128 + j * 16 + l15;
          if (key > q) pv[j][r] = -1e30f;
        }
      }
    }
    float al[4];
#pragma unroll
    for (int r = 0; r < 4; r++) {
      float t0 = fmaxf(fmaxf(pv[0][r], pv[1][r]), fmaxf(pv[2][r], pv[3][r]));
      float t1 = fmaxf(fmaxf(pv[4][r], pv[5][r]), fmaxf(pv[6][r], pv[7][r]));
      float tm = fmaxf(t0, t1);
      tm = fmaxf(tm, __shfl_xor(tm, 1)); tm = fmaxf(tm, __shfl_xor(tm, 2));
      tm = fmaxf(tm, __shfl_xor(tm, 4)); tm = fmaxf(tm, __shfl_xor(tm, 8));
      float mn = fmaxf(mrun[r], tm);
      al[r] = __expf(mrun[r] - mn);
      mrun[r] = mn;
      float ts = 0.f;
#pragma unroll
      for (int j = 0; j < 8; j++) { float p = __expf(pv[j][r] - mn); pv[j][r] = p; ts += p; }
      ts += __shfl_xor(ts, 1); ts += __shfl_xor(ts, 2); ts += __shfl_xor(ts, 4); ts += __shfl_xor(ts, 8);
      lrun[r] = lrun[r] * al[r] + ts;
    }
#pragma unroll
    for (int j = 0; j < 4; j++)
#pragma unroll
      for (int r = 0; r < 4; r++) acco[j][r] *= al[r];
    char* pw = Pl[w];
#pragma unroll
    for (int r = 0; r < 4; r++) {
      int q = l4 * 4 + r;
#pragma unroll
      for (int j = 0; j < 8; j++) {
        int cw = j * 2 + (l15 >> 3);
        int byte = q * 256 + ((cw ^ (q & 15)) * 16) + (l15 & 7) * 2;
        *(u16*)(pw + byte) = f2h(pv[j][r]);
      }
    }
    asm volatile("s_waitcnt lgkmcnt(0)" ::: "memory");
    __builtin_amdgcn_sched_barrier(0);
    __builtin_amdgcn_s_setprio(1);
#pragma unroll
    for (int kk = 0; kk < 4; kk++) {
      h16x8 pa = *reinterpret_cast<const h16x8*>(pw + l15 * 256 + (((kk * 4 + l4) ^ l15) * 16));
#pragma unroll
      for (int j = 0; j < 4; j++) {
        int d = j * 16 + l15;
        int voff = d * 256 + (((kk * 4 + l4) ^ (d & 15)) * 16);
        h16x8 vf = *reinterpret_cast<const h16x8*>(Vb + voff);
        acco[j] = __builtin_amdgcn_mfma_f32_16x16x32_f16(pa, vf, acco[j], 0, 0, 0);
      }
    }
    __builtin_amdgcn_s_setprio(0);
    asm volatile("s_waitcnt vmcnt(0)" ::: "memory");
    __builtin_amdgcn_sched_barrier(0);
    __builtin_amdgcn_s_barrier();
    __builtin_amdgcn_sched_barrier(0);
  }
#undef STAGE1
#pragma unroll
  for (int r = 0; r < 4; r++) {
    float inv = 1.f / lrun[r];
    size_t orow = ((size_t)(b * SQ + qrow + r)) * DM + h * 64;
#pragma unroll
    for (int j = 0; j < 4; j++) O[orow + j * 16 + l15] = f2h(acco[j][r] * inv);
  }
}

// ---------------- Pass-2 attention: 16x16 per (s,h), one wave each (s-major qkv) ----------------
__global__ __launch_bounds__(256) void attn2_k(const u16* __restrict__ qkv, const float* __restrict__ gmask,
                                               u16* __restrict__ O) {
  __shared__ float Pl[4][16][16];
  __shared__ float Vl[4][16][68];
  const int tid = threadIdx.x, w = tid >> 6, lane = tid & 63;
  const int idx = blockIdx.x * 4 + w;
  const int s = idx / NH, h = idx % NH;
  const int l15 = lane & 15, l4 = lane >> 4;
  const size_t base = ((size_t)(s * 16 + l15)) * QKVN + h * 64;
  h16x8 qf0 = *reinterpret_cast<const h16x8*>(qkv + base + 8 * l4);
  h16x8 qf1 = *reinterpret_cast<const h16x8*>(qkv + base + 32 + 8 * l4);
  h16x8 kf0 = *reinterpret_cast<const h16x8*>(qkv + base + DM + 8 * l4);
  h16x8 kf1 = *reinterpret_cast<const h16x8*>(qkv + base + DM + 32 + 8 * l4);
  f32x4 sc = {};
  sc = __builtin_amdgcn_mfma_f32_16x16x32_f16(qf0, kf0, sc, 0, 0, 0);
  sc = __builtin_amdgcn_mfma_f32_16x16x32_f16(qf1, kf1, sc, 0, 0, 0);
  {
    int key = lane >> 2, d0 = (lane & 3) * 16;
    const u16* vsrc = qkv + ((size_t)(s * 16 + key)) * QKVN + 2 * DM + h * 64 + d0;
#pragma unroll
    for (int i = 0; i < 16; i += 4) {
      ushort4 vv = *reinterpret_cast<const ushort4*>(vsrc + i);
      Vl[w][key][d0 + i + 0] = h2f(vv.x);
      Vl[w][key][d0 + i + 1] = h2f(vv.y);
      Vl[w][key][d0 + i + 2] = h2f(vv.z);
      Vl[w][key][d0 + i + 3] = h2f(vv.w);
    }
  }
  const float* gm = gmask + ((size_t)s * NH + h) * 256;
#pragma unroll
  for (int r = 0; r < 4; r++) {
    float v = sc[r] + gm[(l4 * 4 + r) * 16 + l15];
    float mx = v;
    mx = fmaxf(mx, __shfl_xor(mx, 1)); mx = fmaxf(mx, __shfl_xor(mx, 2));
    mx = fmaxf(mx, __shfl_xor(mx, 4)); mx = fmaxf(mx, __shfl_xor(mx, 8));
    float p = __expf(v - mx);
    float su = p;
    su += __shfl_xor(su, 1); su += __shfl_xor(su, 2); su += __shfl_xor(su, 4); su += __shfl_xor(su, 8);
    Pl[w][l4 * 4 + r][l15] = p / su;
  }
  asm volatile("s_waitcnt lgkmcnt(0)" ::: "memory");
  __builtin_amdgcn_sched_barrier(0);
  const int q = lane >> 2, d0 = (lane & 3) * 16;
  float o[16] = {};
#pragma unroll
  for (int key = 0; key < 16; key++) {
    float pp = Pl[w][q][key];
#pragma unroll
    for (int dd = 0; dd < 16; dd += 4) {
      float4 vv = *reinterpret_cast<const float4*>(&Vl[w][key][d0 + dd]);
      o[dd + 0] += pp * vv.x; o[dd + 1] += pp * vv.y; o[dd + 2] += pp * vv.z; o[dd + 3] += pp * vv.w;
    }
  }
  u16* orow = O + ((size_t)(s * 16 + q)) * DM + h * 64 + d0;
#pragma unroll
  for (int i = 0; i < 16; i += 4) {
    ushort4 ov;
    ov.x = f2h(o[i]); ov.y = f2h(o[i + 1]); ov.z = f2h(o[i + 2]); ov.w = f2h(o[i + 3]);
    *reinterpret_cast<ushort4*>(orow + i) = ov;
  }
}

// ---------------- launch ----------------
extern "C" void kernel_launch(void* const* d_in, const int* in_sizes, int n_in,
                              void* d_out, int out_size, void* d_ws, size_t ws_size,
                              hipStream_t stream) {
  const float* hidden = (const float*)d_in[0];
  const int*   pids   = (const int*)d_in[1];
  const float* gmask  = (const float*)d_in[3];
  const float* tq = (const float*)d_in[4];
  const float* tk = (const float*)d_in[5];
  const float* tv = (const float*)d_in[6];
  const float* to_ = (const float*)d_in[7];
  const float* tnw = (const float*)d_in[8];
  const float* gq = (const float*)d_in[9];
  const float* gk = (const float*)d_in[10];
  const float* gv = (const float*)d_in[11];
  const float* go = (const float*)d_in[12];
  const float* gnw = (const float*)d_in[13];
  const float* invf = (const float*)d_in[14];
  float* out = (float*)d_out;
  char* ws = (char*)d_ws;

  u16*   wq1    = (u16*)(ws);                   // 2304x768 fp16 (tnw folded)
  u16*   wo1    = (u16*)(ws + 3538944);         // 768x768
  u16*   wq2    = (u16*)(ws + 4718592);         // (gnw folded)
  u16*   wo2    = (u16*)(ws + 8257536);
  float* tab    = (float*)(ws + 9437184);       // 512x32x2 f32
  u16*   xh     = (u16*)(ws + 9568256);         // 8192x768 fp16 = fp16(hidden)
  u16*   obuf   = (u16*)(ws + 22151168);        // 8192x768 fp16
  u16*   h1     = (u16*)(ws + 34734080);        // 8192x768 fp16 residual spine
  u16*   qkv    = (u16*)(ws + 59899904);        // 8192x2304 fp16
  u16*   vt     = (u16*)(ws + 97648640);        // 192 x 64 x 512 fp16 (12.6 MB)
  float* rs1    = (float*)(ws + 110231552);     // 8192 f32
  float* rs2    = (float*)(ws + 110264320);     // 8192 f32

  const int WN = 768 * 768;
  WPtrs P;
  P.s[0] = tq;  P.d[0] = wq1;
  P.s[1] = tk;  P.d[1] = wq1 + WN;
  P.s[2] = tv;  P.d[2] = wq1 + 2 * WN;
  P.s[3] = to_; P.d[3] = wo1;
  P.s[4] = gq;  P.d[4] = wq2;
  P.s[5] = gk;  P.d[5] = wq2 + WN;
  P.s[6] = gv;  P.d[6] = wq2 + 2 * WN;
  P.s[7] = go;  P.d[7] = wo2;

  // pass 1 (time attention; RMSNorm folded into W' + epilogue row scale; V written transposed)
  prep_k<<<6720, 256, 0, stream>>>(P, invf, tab, hidden, tnw, gnw, xh, rs1);
  gemm_k<0, true, 0, true, true><<<dim3(64, 18), 256, 0, stream>>>(xh, wq1, QKVN, qkv, nullptr, pids, tab, vt, rs1);
  attn1_k<<<dim3(8, 192), 256, 0, stream>>>(qkv, vt, obuf);
  gemm_k<1, false, 0, false, false><<<dim3(64, 6), 256, 0, stream>>>(obuf, wo1, DM, h1, xh, nullptr, nullptr, nullptr, nullptr);

  // pass 2 (group attention; s-major token order; RMSNorm folded)
  rs2_k<<<2048, 256, 0, stream>>>(h1, rs2);
  gemm_k<0, false, 1, false, true><<<dim3(64, 18), 256, 0, stream>>>(h1, wq2, QKVN, qkv, nullptr, nullptr, nullptr, nullptr, rs2);
  attn2_k<<<1536, 256, 0, stream>>>(qkv, gmask, obuf);
  gemm_k<2, false, 2, false, false><<<dim3(64, 6), 256, 0, stream>>>(obuf, wo2, DM, out, h1, nullptr, nullptr, nullptr, nullptr);
}